// Round 1
// baseline (206.927 us; speedup 1.0000x reference)
//
#include <hip/hip_runtime.h>

// PolynomialAttn: B=2,H=16,S=2048,D=64, degree=2, eps=1e-4, fp32 in/out.
// out[s] = (sum_t dots(s,t)^2 * v[t]) / max(sum_t dots(s,t)^2, eps)
// No online softmax needed: numerator and denominator accumulate independently.
// v1: bf16 MFMA 16x16x32, 64x64 Q-tile per 256-thread block, KV tiles of 64.

#define S_LEN 2048
#define DH    64
#define BQ    64
#define BK    64
#define LSTR  72   // LDS row stride in ushorts: 64 + 8 pad (keeps 16B align, breaks bank conflicts)

typedef __bf16 bf16x8 __attribute__((ext_vector_type(8)));
typedef float  f32x4  __attribute__((ext_vector_type(4)));

__device__ __forceinline__ unsigned short f2bf(float f) {
    union { float f; unsigned int u; } x; x.f = f;
    unsigned int u = x.u;
    return (unsigned short)((u + 0x7fffu + ((u >> 16) & 1u)) >> 16);  // RNE
}

__global__ __launch_bounds__(256, 2)
void poly_attn_kernel(const float* __restrict__ qg, const float* __restrict__ kg,
                      const float* __restrict__ vg, float* __restrict__ og)
{
    __shared__ unsigned short Qs[BQ * LSTR];  // Q[i][d]   bf16
    __shared__ unsigned short Ks[BK * LSTR];  // K[j][d]   bf16
    __shared__ unsigned short Vt[DH * LSTR];  // V^T[d][j] bf16
    __shared__ unsigned short Xs[BQ * LSTR];  // X[i][j]   bf16 (dots^2)

    const int tid  = threadIdx.x;
    const int lane = tid & 63;
    const int w    = tid >> 6;     // wave id, owns rows [16w,16w+16)
    const int c    = lane & 15;
    const int quad = lane >> 4;
    const int i0   = w * 16;

    const int bh = blockIdx.y;
    const int q0 = blockIdx.x * BQ;

    const float* qb = qg + ((size_t)bh * S_LEN + q0) * DH;
    const float* kb = kg + (size_t)bh * S_LEN * DH;
    const float* vb = vg + (size_t)bh * S_LEN * DH;
    float*       ob = og + ((size_t)bh * S_LEN + q0) * DH;

    // ---- stage Q tile once (contiguous 64*64 floats) ----
    {
        const float4* qf4 = (const float4*)qb;
        #pragma unroll
        for (int r = 0; r < 4; ++r) {
            int idx = r * 256 + tid;          // float4 index in tile
            int row = idx >> 4, c4 = idx & 15;
            float4 f = qf4[idx];
            ushort4 h;
            h.x = f2bf(f.x); h.y = f2bf(f.y); h.z = f2bf(f.z); h.w = f2bf(f.w);
            *(ushort4*)&Qs[row * LSTR + c4 * 4] = h;
        }
    }

    f32x4 oacc[4];
    #pragma unroll
    for (int t = 0; t < 4; ++t) {
        oacc[t][0] = 0.f; oacc[t][1] = 0.f; oacc[t][2] = 0.f; oacc[t][3] = 0.f;
    }
    float dsum[4] = {0.f, 0.f, 0.f, 0.f};

    for (int t0 = 0; t0 < S_LEN; t0 += BK) {
        __syncthreads();   // previous iteration's PV reads of Ks/Vt/Xs done
        // ---- stage K tile and transposed V tile ----
        {
            const float4* kf4 = (const float4*)(kb + (size_t)t0 * DH);
            const float4* vf4 = (const float4*)(vb + (size_t)t0 * DH);
            #pragma unroll
            for (int r = 0; r < 4; ++r) {
                int idx = r * 256 + tid;
                int row = idx >> 4, c4 = idx & 15;
                float4 f = kf4[idx];
                ushort4 h;
                h.x = f2bf(f.x); h.y = f2bf(f.y); h.z = f2bf(f.z); h.w = f2bf(f.w);
                *(ushort4*)&Ks[row * LSTR + c4 * 4] = h;
                float4 g = vf4[idx];
                int d0 = c4 * 4;
                Vt[(d0 + 0) * LSTR + row] = f2bf(g.x);
                Vt[(d0 + 1) * LSTR + row] = f2bf(g.y);
                Vt[(d0 + 2) * LSTR + row] = f2bf(g.z);
                Vt[(d0 + 3) * LSTR + row] = f2bf(g.w);
            }
        }
        __syncthreads();

        // ---- dots = Q K^T for this wave's 16x64 strip, then X = dots^2 ----
        f32x4 xacc[4];
        #pragma unroll
        for (int t = 0; t < 4; ++t) {
            xacc[t][0] = 0.f; xacc[t][1] = 0.f; xacc[t][2] = 0.f; xacc[t][3] = 0.f;
        }
        #pragma unroll
        for (int k0 = 0; k0 < DH; k0 += 32) {
            // A-frag: A[m=lane&15][k=quad*8+j]
            bf16x8 af = *(const bf16x8*)&Qs[(i0 + c) * LSTR + k0 + quad * 8];
            #pragma unroll
            for (int tn = 0; tn < 4; ++tn) {
                // B-frag: B[k=quad*8+j][n=lane&15] = K[n][k] row-major
                bf16x8 bfg = *(const bf16x8*)&Ks[(tn * 16 + c) * LSTR + k0 + quad * 8];
                xacc[tn] = __builtin_amdgcn_mfma_f32_16x16x32_bf16(af, bfg, xacc[tn], 0, 0, 0);
            }
        }
        // C/D layout: row = quad*4 + r, col = lane&15. Square, accumulate denom,
        // spill X to LDS to convert C-layout -> A-layout for the PV matmul.
        #pragma unroll
        for (int tn = 0; tn < 4; ++tn) {
            #pragma unroll
            for (int r = 0; r < 4; ++r) {
                float xv = xacc[tn][r];
                float xs = xv * xv;
                dsum[r] += xs;
                Xs[(i0 + quad * 4 + r) * LSTR + tn * 16 + c] = f2bf(xs);
            }
        }
        __syncthreads();

        // ---- O += X * V ----
        #pragma unroll
        for (int k0 = 0; k0 < BK; k0 += 32) {
            bf16x8 af = *(const bf16x8*)&Xs[(i0 + c) * LSTR + k0 + quad * 8];
            #pragma unroll
            for (int tn = 0; tn < 4; ++tn) {
                // B[k=j][n=d] = V[j][d] = Vt[d][j], lane reads Vt[n][k..k+7]
                bf16x8 bfg = *(const bf16x8*)&Vt[(tn * 16 + c) * LSTR + k0 + quad * 8];
                oacc[tn] = __builtin_amdgcn_mfma_f32_16x16x32_bf16(af, bfg, oacc[tn], 0, 0, 0);
            }
        }
    }

    // ---- row sums: reduce per-lane partials across the 16 lanes of each quad ----
    #pragma unroll
    for (int r = 0; r < 4; ++r) {
        float s = dsum[r];
        s += __shfl_xor(s, 1);
        s += __shfl_xor(s, 2);
        s += __shfl_xor(s, 4);
        s += __shfl_xor(s, 8);
        dsum[r] = 1.0f / fmaxf(s, 1e-4f);
    }

    // ---- normalize + store (C/D layout: row i0+quad*4+r, col tn*16+c) ----
    #pragma unroll
    for (int tn = 0; tn < 4; ++tn) {
        #pragma unroll
        for (int r = 0; r < 4; ++r) {
            ob[(i0 + quad * 4 + r) * DH + tn * 16 + c] = oacc[tn][r] * dsum[r];
        }
    }
}

extern "C" void kernel_launch(void* const* d_in, const int* in_sizes, int n_in,
                              void* d_out, int out_size, void* d_ws, size_t ws_size,
                              hipStream_t stream) {
    (void)in_sizes; (void)n_in; (void)out_size; (void)d_ws; (void)ws_size;
    const float* q = (const float*)d_in[0];
    const float* k = (const float*)d_in[1];
    const float* v = (const float*)d_in[2];
    float* o = (float*)d_out;
    dim3 grid(S_LEN / BQ, 2 * 16);  // (q-tiles, B*H)
    poly_attn_kernel<<<grid, 256, 0, stream>>>(q, k, v, o);
}

// Round 2
// 171.656 us; speedup vs baseline: 1.2055x; 1.2055x over previous
//
#include <hip/hip_runtime.h>

// PolynomialAttn: B=2,H=16,S=2048,D=64, degree=2, eps=1e-4, fp32 in/out.
// v2: prepass converts K->bf16 and V->V^T bf16 in d_ws; main kernel BQ=128,
// Q A-frags in registers, conflict-free LDS staging, 16x16x32 bf16 MFMA.

#define S_LEN 2048
#define DH    64
#define BQ    128
#define BK    64
#define LSTR  72        // LDS row stride in ushorts (pad 8: keeps 16B align, balances banks)
#define PSTR  65        // prepass transpose LDS stride (odd: conflict-free scalar r/w)
#define BH_N  32        // B*H
#define PER_BH (S_LEN * DH)   // 131072 elems

typedef __bf16 bf16x8 __attribute__((ext_vector_type(8)));
typedef float  f32x4  __attribute__((ext_vector_type(4)));

__device__ __forceinline__ unsigned short f2bf(float f) {
    union { float f; unsigned int u; } x; x.f = f;
    unsigned int u = x.u;
    return (unsigned short)((u + 0x7fffu + ((u >> 16) & 1u)) >> 16);  // RNE
}

// ---------------- prepass: K fp32 -> bf16 flat copy ----------------
__global__ __launch_bounds__(256)
void conv_k_kernel(const float* __restrict__ kg, unsigned short* __restrict__ kbf)
{
    int i0 = (blockIdx.x * 256 + threadIdx.x) * 16;   // 16 floats per thread
    const float4* src = (const float4*)(kg + i0);
    union { unsigned short h[8]; uint4 v; } u0, u1;
    float4 a = src[0], b = src[1], c = src[2], d = src[3];
    u0.h[0]=f2bf(a.x); u0.h[1]=f2bf(a.y); u0.h[2]=f2bf(a.z); u0.h[3]=f2bf(a.w);
    u0.h[4]=f2bf(b.x); u0.h[5]=f2bf(b.y); u0.h[6]=f2bf(b.z); u0.h[7]=f2bf(b.w);
    u1.h[0]=f2bf(c.x); u1.h[1]=f2bf(c.y); u1.h[2]=f2bf(c.z); u1.h[3]=f2bf(c.w);
    u1.h[4]=f2bf(d.x); u1.h[5]=f2bf(d.y); u1.h[6]=f2bf(d.z); u1.h[7]=f2bf(d.w);
    uint4* dst = (uint4*)(kbf + i0);
    dst[0] = u0.v; dst[1] = u1.v;
}

// ---------------- prepass: V [bh][S][D] fp32 -> V^T [bh][D][S] bf16 ----------------
__global__ __launch_bounds__(256)
void transpose_v_kernel(const float* __restrict__ vg, unsigned short* __restrict__ vt)
{
    __shared__ unsigned short Ls[64 * PSTR];
    const int tid = threadIdx.x;
    const int bh  = blockIdx.y;
    const int t0  = blockIdx.x * 64;          // S-tile origin
    const float* vb = vg + (size_t)bh * PER_BH + (size_t)t0 * DH;

    #pragma unroll
    for (int r = 0; r < 4; ++r) {
        int idx = r * 256 + tid;              // float4 index in 64x64 tile
        int row = idx >> 4, c4 = idx & 15;
        float4 f = ((const float4*)vb)[idx];
        unsigned short* p = &Ls[row * PSTR + c4 * 4];
        p[0] = f2bf(f.x); p[1] = f2bf(f.y); p[2] = f2bf(f.z); p[3] = f2bf(f.w);
    }
    __syncthreads();
    #pragma unroll
    for (int r = 0; r < 2; ++r) {
        int idx = r * 256 + tid;              // ushort8 chunk index: 64 d-rows x 8 chunks
        int d = idx >> 3, j8 = idx & 7;
        union { unsigned short h[8]; uint4 v; } u;
        #pragma unroll
        for (int jj = 0; jj < 8; ++jj) u.h[jj] = Ls[(j8 * 8 + jj) * PSTR + d];
        *(uint4*)(vt + (size_t)bh * PER_BH + (size_t)d * S_LEN + t0 + j8 * 8) = u.v;
    }
}

// ---------------- main kernel ----------------
__global__ __launch_bounds__(256, 2)
void poly_attn_main(const float* __restrict__ qg,
                    const unsigned short* __restrict__ kbf,
                    const unsigned short* __restrict__ vtbf,
                    float* __restrict__ og)
{
    __shared__ unsigned short Ks[BK * LSTR];   // K[j][d] bf16
    __shared__ unsigned short Vts[DH * LSTR];  // V^T[d][j] bf16
    __shared__ unsigned short Xs[BQ * LSTR];   // X[i][j] bf16

    const int tid  = threadIdx.x;
    const int lane = tid & 63;
    const int w    = tid >> 6;        // wave id: owns Q rows [32w, 32w+32)
    const int c    = lane & 15;
    const int quad = lane >> 4;

    const int bh = blockIdx.y;
    const int q0 = blockIdx.x * BQ;

    const float* qb = qg + ((size_t)bh * S_LEN + q0) * DH;
    const unsigned short* kb  = kbf  + (size_t)bh * PER_BH;
    const unsigned short* vtb = vtbf + (size_t)bh * PER_BH;
    float* ob = og + ((size_t)bh * S_LEN + q0) * DH;

    // ---- preload Q A-fragments into registers (once) ----
    // A-frag layout: A[m=c][k=quad*8+j]; strips s=0,1 rows 32w+16s+c; k halves k0=0,32
    bf16x8 qfrag[2][2];
    #pragma unroll
    for (int s = 0; s < 2; ++s) {
        #pragma unroll
        for (int kh = 0; kh < 2; ++kh) {
            const float* qp = qb + (32 * w + 16 * s + c) * DH + kh * 32 + quad * 8;
            float4 f0 = *(const float4*)qp;
            float4 f1 = *(const float4*)(qp + 4);
            union { unsigned short h[8]; bf16x8 v; } u;
            u.h[0]=f2bf(f0.x); u.h[1]=f2bf(f0.y); u.h[2]=f2bf(f0.z); u.h[3]=f2bf(f0.w);
            u.h[4]=f2bf(f1.x); u.h[5]=f2bf(f1.y); u.h[6]=f2bf(f1.z); u.h[7]=f2bf(f1.w);
            qfrag[s][kh] = u.v;
        }
    }

    f32x4 oacc[2][4];
    #pragma unroll
    for (int s = 0; s < 2; ++s)
        #pragma unroll
        for (int t = 0; t < 4; ++t) {
            oacc[s][t][0]=0.f; oacc[s][t][1]=0.f; oacc[s][t][2]=0.f; oacc[s][t][3]=0.f;
        }
    float dsum[2][4] = {{0.f,0.f,0.f,0.f},{0.f,0.f,0.f,0.f}};

    // staging indices (bf16 global -> LDS, 16B chunks, 2 per thread per array)
    const int srow = tid >> 3;        // 0..31  (row pair base; +32 on second iter)
    const int sc8  = tid & 7;         // 16B chunk within 64-elem row

    for (int t0 = 0; t0 < S_LEN; t0 += BK) {
        __syncthreads();   // all waves done reading previous Ks/Vts
        // ---- stage K and V^T tiles (bf16, vectorized, conflict-balanced) ----
        #pragma unroll
        for (int it = 0; it < 2; ++it) {
            int row = srow + it * 32;
            uint4 kv = *(const uint4*)(kb + (size_t)(t0 + row) * DH + sc8 * 8);
            *(uint4*)&Ks[row * LSTR + sc8 * 8] = kv;
            uint4 vv = *(const uint4*)(vtb + (size_t)row * S_LEN + t0 + sc8 * 8);
            *(uint4*)&Vts[row * LSTR + sc8 * 8] = vv;
        }
        __syncthreads();

        // ---- QK^T: X strips [32w..32w+32) x 64 ----
        f32x4 xacc[2][4];
        #pragma unroll
        for (int s = 0; s < 2; ++s)
            #pragma unroll
            for (int t = 0; t < 4; ++t) {
                xacc[s][t][0]=0.f; xacc[s][t][1]=0.f; xacc[s][t][2]=0.f; xacc[s][t][3]=0.f;
            }
        #pragma unroll
        for (int kh = 0; kh < 2; ++kh) {
            #pragma unroll
            for (int tn = 0; tn < 4; ++tn) {
                bf16x8 bfg = *(const bf16x8*)&Ks[(tn * 16 + c) * LSTR + kh * 32 + quad * 8];
                #pragma unroll
                for (int s = 0; s < 2; ++s)
                    xacc[s][tn] = __builtin_amdgcn_mfma_f32_16x16x32_bf16(qfrag[s][kh], bfg, xacc[s][tn], 0, 0, 0);
            }
        }

        // ---- square, accumulate denom, spill X (C-layout -> row-major LDS) ----
        // Only this wave reads its Xs rows; no barrier needed (in-wave LDS ordering).
        #pragma unroll
        for (int s = 0; s < 2; ++s)
            #pragma unroll
            for (int tn = 0; tn < 4; ++tn)
                #pragma unroll
                for (int r = 0; r < 4; ++r) {
                    float xv = xacc[s][tn][r];
                    float xs = xv * xv;
                    dsum[s][r] += xs;
                    Xs[(32 * w + 16 * s + quad * 4 + r) * LSTR + tn * 16 + c] = f2bf(xs);
                }

        // ---- O += X * V ----
        #pragma unroll
        for (int kh = 0; kh < 2; ++kh) {
            bf16x8 aX[2];
            #pragma unroll
            for (int s = 0; s < 2; ++s)
                aX[s] = *(const bf16x8*)&Xs[(32 * w + 16 * s + c) * LSTR + kh * 32 + quad * 8];
            #pragma unroll
            for (int tn = 0; tn < 4; ++tn) {
                bf16x8 bfg = *(const bf16x8*)&Vts[(tn * 16 + c) * LSTR + kh * 32 + quad * 8];
                #pragma unroll
                for (int s = 0; s < 2; ++s)
                    oacc[s][tn] = __builtin_amdgcn_mfma_f32_16x16x32_bf16(aX[s], bfg, oacc[s][tn], 0, 0, 0);
            }
        }
    }

    // ---- row denominators: reduce across the 16 lanes of each quad-row group ----
    #pragma unroll
    for (int s = 0; s < 2; ++s)
        #pragma unroll
        for (int r = 0; r < 4; ++r) {
            float t = dsum[s][r];
            t += __shfl_xor(t, 1);
            t += __shfl_xor(t, 2);
            t += __shfl_xor(t, 4);
            t += __shfl_xor(t, 8);
            dsum[s][r] = 1.0f / fmaxf(t, 1e-4f);
        }

    // ---- normalize + store ----
    #pragma unroll
    for (int s = 0; s < 2; ++s)
        #pragma unroll
        for (int tn = 0; tn < 4; ++tn)
            #pragma unroll
            for (int r = 0; r < 4; ++r)
                ob[(32 * w + 16 * s + quad * 4 + r) * DH + tn * 16 + c] = oacc[s][tn][r] * dsum[s][r];
}

// ---------------- fallback (round-1 kernel, used if ws too small) ----------------
__global__ __launch_bounds__(256, 2)
void poly_attn_fallback(const float* __restrict__ qg, const float* __restrict__ kg,
                        const float* __restrict__ vg, float* __restrict__ og)
{
    __shared__ unsigned short Qs[64 * LSTR];
    __shared__ unsigned short Ks[64 * LSTR];
    __shared__ unsigned short Vt[64 * LSTR];
    __shared__ unsigned short Xs[64 * LSTR];

    const int tid  = threadIdx.x;
    const int lane = tid & 63;
    const int w    = tid >> 6;
    const int c    = lane & 15;
    const int quad = lane >> 4;
    const int i0   = w * 16;

    const int bh = blockIdx.y;
    const int q0 = blockIdx.x * 64;

    const float* qb = qg + ((size_t)bh * S_LEN + q0) * DH;
    const float* kb = kg + (size_t)bh * S_LEN * DH;
    const float* vb = vg + (size_t)bh * S_LEN * DH;
    float*       ob = og + ((size_t)bh * S_LEN + q0) * DH;

    {
        const float4* qf4 = (const float4*)qb;
        #pragma unroll
        for (int r = 0; r < 4; ++r) {
            int idx = r * 256 + tid;
            int row = idx >> 4, c4 = idx & 15;
            float4 f = qf4[idx];
            ushort4 h;
            h.x = f2bf(f.x); h.y = f2bf(f.y); h.z = f2bf(f.z); h.w = f2bf(f.w);
            *(ushort4*)&Qs[row * LSTR + c4 * 4] = h;
        }
    }

    f32x4 oacc[4];
    #pragma unroll
    for (int t = 0; t < 4; ++t) { oacc[t][0]=0.f; oacc[t][1]=0.f; oacc[t][2]=0.f; oacc[t][3]=0.f; }
    float dsum[4] = {0.f, 0.f, 0.f, 0.f};

    for (int t0 = 0; t0 < S_LEN; t0 += 64) {
        __syncthreads();
        {
            const float4* kf4 = (const float4*)(kb + (size_t)t0 * DH);
            const float4* vf4 = (const float4*)(vb + (size_t)t0 * DH);
            #pragma unroll
            for (int r = 0; r < 4; ++r) {
                int idx = r * 256 + tid;
                int row = idx >> 4, c4 = idx & 15;
                float4 f = kf4[idx];
                ushort4 h;
                h.x = f2bf(f.x); h.y = f2bf(f.y); h.z = f2bf(f.z); h.w = f2bf(f.w);
                *(ushort4*)&Ks[row * LSTR + c4 * 4] = h;
                float4 g = vf4[idx];
                int d0 = c4 * 4;
                Vt[(d0 + 0) * LSTR + row] = f2bf(g.x);
                Vt[(d0 + 1) * LSTR + row] = f2bf(g.y);
                Vt[(d0 + 2) * LSTR + row] = f2bf(g.z);
                Vt[(d0 + 3) * LSTR + row] = f2bf(g.w);
            }
        }
        __syncthreads();

        f32x4 xacc[4];
        #pragma unroll
        for (int t = 0; t < 4; ++t) { xacc[t][0]=0.f; xacc[t][1]=0.f; xacc[t][2]=0.f; xacc[t][3]=0.f; }
        #pragma unroll
        for (int k0 = 0; k0 < 64; k0 += 32) {
            bf16x8 af = *(const bf16x8*)&Qs[(i0 + c) * LSTR + k0 + quad * 8];
            #pragma unroll
            for (int tn = 0; tn < 4; ++tn) {
                bf16x8 bfg = *(const bf16x8*)&Ks[(tn * 16 + c) * LSTR + k0 + quad * 8];
                xacc[tn] = __builtin_amdgcn_mfma_f32_16x16x32_bf16(af, bfg, xacc[tn], 0, 0, 0);
            }
        }
        #pragma unroll
        for (int tn = 0; tn < 4; ++tn)
            #pragma unroll
            for (int r = 0; r < 4; ++r) {
                float xv = xacc[tn][r];
                float xs = xv * xv;
                dsum[r] += xs;
                Xs[(i0 + quad * 4 + r) * LSTR + tn * 16 + c] = f2bf(xs);
            }
        __syncthreads();

        #pragma unroll
        for (int k0 = 0; k0 < 64; k0 += 32) {
            bf16x8 af = *(const bf16x8*)&Xs[(i0 + c) * LSTR + k0 + quad * 8];
            #pragma unroll
            for (int tn = 0; tn < 4; ++tn) {
                bf16x8 bfg = *(const bf16x8*)&Vt[(tn * 16 + c) * LSTR + k0 + quad * 8];
                oacc[tn] = __builtin_amdgcn_mfma_f32_16x16x32_bf16(af, bfg, oacc[tn], 0, 0, 0);
            }
        }
    }

    #pragma unroll
    for (int r = 0; r < 4; ++r) {
        float s = dsum[r];
        s += __shfl_xor(s, 1);
        s += __shfl_xor(s, 2);
        s += __shfl_xor(s, 4);
        s += __shfl_xor(s, 8);
        dsum[r] = 1.0f / fmaxf(s, 1e-4f);
    }
    #pragma unroll
    for (int tn = 0; tn < 4; ++tn)
        #pragma unroll
        for (int r = 0; r < 4; ++r)
            ob[(i0 + quad * 4 + r) * DH + tn * 16 + c] = oacc[tn][r] * dsum[r];
}

extern "C" void kernel_launch(void* const* d_in, const int* in_sizes, int n_in,
                              void* d_out, int out_size, void* d_ws, size_t ws_size,
                              hipStream_t stream) {
    (void)in_sizes; (void)n_in; (void)out_size;
    const float* q = (const float*)d_in[0];
    const float* k = (const float*)d_in[1];
    const float* v = (const float*)d_in[2];
    float* o = (float*)d_out;

    const size_t elems = (size_t)BH_N * PER_BH;         // 4,194,304
    const size_t need  = 2 * elems * sizeof(unsigned short); // 16.78 MB

    if (ws_size >= need) {
        unsigned short* kbf = (unsigned short*)d_ws;
        unsigned short* vtb = kbf + elems;
        conv_k_kernel<<<dim3(elems / (256 * 16)), 256, 0, stream>>>(k, kbf);
        transpose_v_kernel<<<dim3(S_LEN / 64, BH_N), 256, 0, stream>>>(v, vtb);
        poly_attn_main<<<dim3(S_LEN / BQ, BH_N), 256, 0, stream>>>(q, kbf, vtb, o);
    } else {
        poly_attn_fallback<<<dim3(S_LEN / 64, BH_N), 256, 0, stream>>>(q, k, v, o);
    }
}

// Round 3
// 144.187 us; speedup vs baseline: 1.4351x; 1.1905x over previous
//
#include <hip/hip_runtime.h>

// PolynomialAttn: B=2,H=16,S=2048,D=64, degree=2, eps=1e-4, fp32 in/out.
// v3: X^T = K*Q^T operand swap => X spill is b64 (4 consecutive j per lane);
// double-buffered K/V LDS (1 barrier/tile) w/ register prefetch; packed bf16
// cvt; single fused prepass launch (K->bf16, V->V^T bf16 in d_ws).

#define S_LEN 2048
#define DH    64
#define BQ    128
#define BK    64
#define LSTR  72        // LDS row stride in ushorts (pad 8: 16B-aligned, 2-way-max bank alias)
#define PSTR  65        // prepass transpose LDS stride
#define BH_N  32        // B*H
#define PER_BH (S_LEN * DH)   // 131072 elems
#define NT    (S_LEN / BK)    // 32 KV tiles

typedef __bf16 bf16x8 __attribute__((ext_vector_type(8)));
typedef __bf16 bf16x2 __attribute__((ext_vector_type(2)));
typedef float  f32x4  __attribute__((ext_vector_type(4)));

__device__ __forceinline__ unsigned short f2bf(float f) {
    union { float f; unsigned int u; } x; x.f = f;
    unsigned int u = x.u;
    return (unsigned short)((u + 0x7fffu + ((u >> 16) & 1u)) >> 16);  // RNE
}

__device__ __forceinline__ unsigned int pack2bf(float lo, float hi) {
#if __has_builtin(__builtin_amdgcn_cvt_pk_bf16_f32)
    bf16x2 p = __builtin_amdgcn_cvt_pk_bf16_f32(lo, hi);
    union { bf16x2 v; unsigned int u; } c; c.v = p;
    return c.u;
#else
    return (unsigned int)f2bf(lo) | ((unsigned int)f2bf(hi) << 16);
#endif
}

// ---------------- fused prepass: K fp32->bf16 copy + V fp32 -> V^T bf16 ----------------
// grid (S_LEN/64, BH_N), 256 threads. Each block handles one 64-row slice of
// one bh: converts K rows t0..t0+63 and transposes V rows t0..t0+63.
__global__ __launch_bounds__(256)
void prepass_kernel(const float* __restrict__ kg, const float* __restrict__ vg,
                    unsigned short* __restrict__ kbf, unsigned short* __restrict__ vt)
{
    __shared__ unsigned short Ls[64 * PSTR];
    const int tid = threadIdx.x;
    const int bh  = blockIdx.y;
    const int t0  = blockIdx.x * 64;
    const size_t base = (size_t)bh * PER_BH + (size_t)t0 * DH;

    // --- K convert: 64*64 contiguous floats -> bf16 ---
    {
        const float4* src = (const float4*)(kg + base + (size_t)tid * 16);
        float4 a = src[0], b = src[1], c = src[2], d = src[3];
        union { unsigned short h[8]; uint4 v; } u0, u1;
        u0.h[0]=f2bf(a.x); u0.h[1]=f2bf(a.y); u0.h[2]=f2bf(a.z); u0.h[3]=f2bf(a.w);
        u0.h[4]=f2bf(b.x); u0.h[5]=f2bf(b.y); u0.h[6]=f2bf(b.z); u0.h[7]=f2bf(b.w);
        u1.h[0]=f2bf(c.x); u1.h[1]=f2bf(c.y); u1.h[2]=f2bf(c.z); u1.h[3]=f2bf(c.w);
        u1.h[4]=f2bf(d.x); u1.h[5]=f2bf(d.y); u1.h[6]=f2bf(d.z); u1.h[7]=f2bf(d.w);
        uint4* dst = (uint4*)(kbf + base + (size_t)tid * 16);
        dst[0] = u0.v; dst[1] = u1.v;
    }

    // --- V transpose: [64 s][64 d] -> vt[bh][d][S] ---
    const float* vb = vg + base;
    #pragma unroll
    for (int r = 0; r < 4; ++r) {
        int idx = r * 256 + tid;              // float4 index in 64x64 tile
        int row = idx >> 4, c4 = idx & 15;
        float4 f = ((const float4*)vb)[idx];
        unsigned short* p = &Ls[row * PSTR + c4 * 4];
        p[0] = f2bf(f.x); p[1] = f2bf(f.y); p[2] = f2bf(f.z); p[3] = f2bf(f.w);
    }
    __syncthreads();
    #pragma unroll
    for (int r = 0; r < 2; ++r) {
        int idx = r * 256 + tid;              // 64 d-rows x 8 chunks of 8
        int d = idx >> 3, j8 = idx & 7;
        union { unsigned short h[8]; uint4 v; } u;
        #pragma unroll
        for (int jj = 0; jj < 8; ++jj) u.h[jj] = Ls[(j8 * 8 + jj) * PSTR + d];
        *(uint4*)(vt + (size_t)bh * PER_BH + (size_t)d * S_LEN + t0 + j8 * 8) = u.v;
    }
}

// ---------------- main kernel ----------------
__global__ __launch_bounds__(256, 2)
void poly_attn_main(const float* __restrict__ qg,
                    const unsigned short* __restrict__ kbf,
                    const unsigned short* __restrict__ vtbf,
                    float* __restrict__ og)
{
    __shared__ unsigned short Ks[2][BK * LSTR];   // K[j][d] bf16, double-buffered
    __shared__ unsigned short Vts[2][DH * LSTR];  // V^T[d][j] bf16, double-buffered
    __shared__ unsigned short Xs[BQ * LSTR];      // X[i][j] bf16 (wave-private rows)

    const int tid  = threadIdx.x;
    const int lane = tid & 63;
    const int w    = tid >> 6;        // wave id: owns Q rows [32w, 32w+32)
    const int c    = lane & 15;
    const int quad = lane >> 4;

    const int bh = blockIdx.y;
    const int q0 = blockIdx.x * BQ;

    const float* qb = qg + ((size_t)bh * S_LEN + q0) * DH;
    const unsigned short* kb  = kbf  + (size_t)bh * PER_BH;
    const unsigned short* vtb = vtbf + (size_t)bh * PER_BH;
    float* ob = og + ((size_t)bh * S_LEN + q0) * DH;

    // ---- preload Q fragments into registers (serve as B-operand of X^T = K Q^T) ----
    // frag: lane holds Q[i0s + c][kh*32 + quad*8 + j], j=0..7
    bf16x8 qfrag[2][2];
    #pragma unroll
    for (int s = 0; s < 2; ++s) {
        #pragma unroll
        for (int kh = 0; kh < 2; ++kh) {
            const float* qp = qb + (32 * w + 16 * s + c) * DH + kh * 32 + quad * 8;
            float4 f0 = *(const float4*)qp;
            float4 f1 = *(const float4*)(qp + 4);
            union { unsigned int d[4]; bf16x8 v; } u;
            u.d[0] = pack2bf(f0.x, f0.y);
            u.d[1] = pack2bf(f0.z, f0.w);
            u.d[2] = pack2bf(f1.x, f1.y);
            u.d[3] = pack2bf(f1.z, f1.w);
            qfrag[s][kh] = u.v;
        }
    }

    f32x4 oacc[2][4];
    #pragma unroll
    for (int s = 0; s < 2; ++s)
        #pragma unroll
        for (int t = 0; t < 4; ++t) {
            oacc[s][t][0]=0.f; oacc[s][t][1]=0.f; oacc[s][t][2]=0.f; oacc[s][t][3]=0.f;
        }
    float dsum[2] = {0.f, 0.f};

    // staging: 256 threads move 64x64 bf16 K-tile + 64x64 V^T-tile, 16B chunks
    const int srow = tid >> 3;        // 0..31 (+32 on second pass)
    const int sc8  = tid & 7;

    // ---- prologue: load tile 0, stage into buffer 0 ----
    uint4 kreg[2], vreg[2];
    #pragma unroll
    for (int it = 0; it < 2; ++it) {
        int row = srow + it * 32;
        kreg[it] = *(const uint4*)(kb + (size_t)row * DH + sc8 * 8);
        vreg[it] = *(const uint4*)(vtb + (size_t)row * S_LEN + sc8 * 8);
    }
    #pragma unroll
    for (int it = 0; it < 2; ++it) {
        int row = srow + it * 32;
        *(uint4*)&Ks[0][row * LSTR + sc8 * 8] = kreg[it];
        *(uint4*)&Vts[0][row * LSTR + sc8 * 8] = vreg[it];
    }
    __syncthreads();

    for (int t = 0; t < NT; ++t) {
        const int cur = t & 1;
        // ---- prefetch next tile into registers (no wait; hides under compute) ----
        if (t + 1 < NT) {
            const int t0n = (t + 1) * BK;
            #pragma unroll
            for (int it = 0; it < 2; ++it) {
                int row = srow + it * 32;
                kreg[it] = *(const uint4*)(kb + (size_t)(t0n + row) * DH + sc8 * 8);
                vreg[it] = *(const uint4*)(vtb + (size_t)row * S_LEN + t0n + sc8 * 8);
            }
        }

        // ---- X^T = K Q^T : C-layout row = j_local = quad*4+r, col = i = i0s + c ----
        f32x4 xaccT[2][4];   // [s][jt]
        #pragma unroll
        for (int s = 0; s < 2; ++s)
            #pragma unroll
            for (int jt = 0; jt < 4; ++jt) {
                xaccT[s][jt][0]=0.f; xaccT[s][jt][1]=0.f; xaccT[s][jt][2]=0.f; xaccT[s][jt][3]=0.f;
            }
        #pragma unroll
        for (int kh = 0; kh < 2; ++kh) {
            #pragma unroll
            for (int jt = 0; jt < 4; ++jt) {
                bf16x8 kfrag = *(const bf16x8*)&Ks[cur][(jt * 16 + c) * LSTR + kh * 32 + quad * 8];
                #pragma unroll
                for (int s = 0; s < 2; ++s)
                    xaccT[s][jt] = __builtin_amdgcn_mfma_f32_16x16x32_bf16(kfrag, qfrag[s][kh], xaccT[s][jt], 0, 0, 0);
            }
        }

        // ---- square, accumulate denom (per-column i = c), b64 spill to Xs ----
        #pragma unroll
        for (int s = 0; s < 2; ++s) {
            #pragma unroll
            for (int jt = 0; jt < 4; ++jt) {
                float x0 = xaccT[s][jt][0], x1 = xaccT[s][jt][1];
                float x2 = xaccT[s][jt][2], x3 = xaccT[s][jt][3];
                x0 *= x0; x1 *= x1; x2 *= x2; x3 *= x3;
                dsum[s] += (x0 + x1) + (x2 + x3);
                uint2 p;
                p.x = pack2bf(x0, x1);
                p.y = pack2bf(x2, x3);
                *(uint2*)&Xs[(32 * w + 16 * s + c) * LSTR + jt * 16 + quad * 4] = p;
            }
        }

        // ---- O += X V  (A = X from Xs, B = V via Vts rows; wave-private Xs rows) ----
        #pragma unroll
        for (int kh = 0; kh < 2; ++kh) {
            bf16x8 aX[2];
            #pragma unroll
            for (int s = 0; s < 2; ++s)
                aX[s] = *(const bf16x8*)&Xs[(32 * w + 16 * s + c) * LSTR + kh * 32 + quad * 8];
            #pragma unroll
            for (int tn = 0; tn < 4; ++tn) {
                bf16x8 vfrag = *(const bf16x8*)&Vts[cur][(tn * 16 + c) * LSTR + kh * 32 + quad * 8];
                #pragma unroll
                for (int s = 0; s < 2; ++s)
                    oacc[s][tn] = __builtin_amdgcn_mfma_f32_16x16x32_bf16(aX[s], vfrag, oacc[s][tn], 0, 0, 0);
            }
        }

        // ---- stage prefetched tile into the other buffer; one barrier per tile ----
        if (t + 1 < NT) {
            #pragma unroll
            for (int it = 0; it < 2; ++it) {
                int row = srow + it * 32;
                *(uint4*)&Ks[cur ^ 1][row * LSTR + sc8 * 8] = kreg[it];
                *(uint4*)&Vts[cur ^ 1][row * LSTR + sc8 * 8] = vreg[it];
            }
            __syncthreads();
        }
    }

    // ---- denominators: dsum[s] is partial for column i = i0s + c; reduce across quads ----
    #pragma unroll
    for (int s = 0; s < 2; ++s) {
        float tsum = dsum[s];
        tsum += __shfl_xor(tsum, 16);
        tsum += __shfl_xor(tsum, 32);
        dsum[s] = 1.0f / fmaxf(tsum, 1e-4f);   // every lane: inv denom for i = i0s + c
    }

    // ---- normalize + store. oacc C-layout: row i0s + quad*4+r, col tn*16+c ----
    #pragma unroll
    for (int s = 0; s < 2; ++s) {
        float inv[4];
        #pragma unroll
        for (int r = 0; r < 4; ++r)
            inv[r] = __shfl(dsum[s], quad * 4 + r);   // from quad-0 lane holding that i
        #pragma unroll
        for (int tn = 0; tn < 4; ++tn)
            #pragma unroll
            for (int r = 0; r < 4; ++r)
                ob[(32 * w + 16 * s + quad * 4 + r) * DH + tn * 16 + c] = oacc[s][tn][r] * inv[r];
    }
}

// ---------------- fallback (self-contained, used if ws too small) ----------------
__global__ __launch_bounds__(256, 2)
void poly_attn_fallback(const float* __restrict__ qg, const float* __restrict__ kg,
                        const float* __restrict__ vg, float* __restrict__ og)
{
    __shared__ unsigned short Qs[64 * LSTR];
    __shared__ unsigned short Ksl[64 * LSTR];
    __shared__ unsigned short Vt[64 * LSTR];
    __shared__ unsigned short Xsl[64 * LSTR];

    const int tid  = threadIdx.x;
    const int lane = tid & 63;
    const int w    = tid >> 6;
    const int c    = lane & 15;
    const int quad = lane >> 4;
    const int i0   = w * 16;

    const int bh = blockIdx.y;
    const int q0 = blockIdx.x * 64;

    const float* qb = qg + ((size_t)bh * S_LEN + q0) * DH;
    const float* kb = kg + (size_t)bh * S_LEN * DH;
    const float* vb = vg + (size_t)bh * S_LEN * DH;
    float*       ob = og + ((size_t)bh * S_LEN + q0) * DH;

    {
        const float4* qf4 = (const float4*)qb;
        #pragma unroll
        for (int r = 0; r < 4; ++r) {
            int idx = r * 256 + tid;
            int row = idx >> 4, c4 = idx & 15;
            float4 f = qf4[idx];
            ushort4 h;
            h.x = f2bf(f.x); h.y = f2bf(f.y); h.z = f2bf(f.z); h.w = f2bf(f.w);
            *(ushort4*)&Qs[row * LSTR + c4 * 4] = h;
        }
    }

    f32x4 oacc[4];
    #pragma unroll
    for (int t = 0; t < 4; ++t) { oacc[t][0]=0.f; oacc[t][1]=0.f; oacc[t][2]=0.f; oacc[t][3]=0.f; }
    float dsum[4] = {0.f, 0.f, 0.f, 0.f};

    for (int t0 = 0; t0 < S_LEN; t0 += 64) {
        __syncthreads();
        {
            const float4* kf4 = (const float4*)(kb + (size_t)t0 * DH);
            const float4* vf4 = (const float4*)(vb + (size_t)t0 * DH);
            #pragma unroll
            for (int r = 0; r < 4; ++r) {
                int idx = r * 256 + tid;
                int row = idx >> 4, c4 = idx & 15;
                float4 f = kf4[idx];
                ushort4 h;
                h.x = f2bf(f.x); h.y = f2bf(f.y); h.z = f2bf(f.z); h.w = f2bf(f.w);
                *(ushort4*)&Ksl[row * LSTR + c4 * 4] = h;
                float4 g = vf4[idx];
                int d0 = c4 * 4;
                Vt[(d0 + 0) * LSTR + row] = f2bf(g.x);
                Vt[(d0 + 1) * LSTR + row] = f2bf(g.y);
                Vt[(d0 + 2) * LSTR + row] = f2bf(g.z);
                Vt[(d0 + 3) * LSTR + row] = f2bf(g.w);
            }
        }
        __syncthreads();

        f32x4 xacc[4];
        #pragma unroll
        for (int t = 0; t < 4; ++t) { xacc[t][0]=0.f; xacc[t][1]=0.f; xacc[t][2]=0.f; xacc[t][3]=0.f; }
        #pragma unroll
        for (int k0 = 0; k0 < 64; k0 += 32) {
            bf16x8 af = *(const bf16x8*)&Qs[(i0 + c) * LSTR + k0 + quad * 8];
            #pragma unroll
            for (int tn = 0; tn < 4; ++tn) {
                bf16x8 bfg = *(const bf16x8*)&Ksl[(tn * 16 + c) * LSTR + k0 + quad * 8];
                xacc[tn] = __builtin_amdgcn_mfma_f32_16x16x32_bf16(af, bfg, xacc[tn], 0, 0, 0);
            }
        }
        #pragma unroll
        for (int tn = 0; tn < 4; ++tn)
            #pragma unroll
            for (int r = 0; r < 4; ++r) {
                float xv = xacc[tn][r];
                float xs = xv * xv;
                dsum[r] += xs;
                Xsl[(i0 + quad * 4 + r) * LSTR + tn * 16 + c] = f2bf(xs);
            }
        __syncthreads();

        #pragma unroll
        for (int k0 = 0; k0 < 64; k0 += 32) {
            bf16x8 af = *(const bf16x8*)&Xsl[(i0 + c) * LSTR + k0 + quad * 8];
            #pragma unroll
            for (int tn = 0; tn < 4; ++tn) {
                bf16x8 bfg = *(const bf16x8*)&Vt[(tn * 16 + c) * LSTR + k0 + quad * 8];
                oacc[tn] = __builtin_amdgcn_mfma_f32_16x16x32_bf16(af, bfg, oacc[tn], 0, 0, 0);
            }
        }
    }

    #pragma unroll
    for (int r = 0; r < 4; ++r) {
        float s = dsum[r];
        s += __shfl_xor(s, 1);
        s += __shfl_xor(s, 2);
        s += __shfl_xor(s, 4);
        s += __shfl_xor(s, 8);
        dsum[r] = 1.0f / fmaxf(s, 1e-4f);
    }
    #pragma unroll
    for (int tn = 0; tn < 4; ++tn)
        #pragma unroll
        for (int r = 0; r < 4; ++r)
            ob[(i0 + quad * 4 + r) * DH + tn * 16 + c] = oacc[tn][r] * dsum[r];
}

extern "C" void kernel_launch(void* const* d_in, const int* in_sizes, int n_in,
                              void* d_out, int out_size, void* d_ws, size_t ws_size,
                              hipStream_t stream) {
    (void)in_sizes; (void)n_in; (void)out_size;
    const float* q = (const float*)d_in[0];
    const float* k = (const float*)d_in[1];
    const float* v = (const float*)d_in[2];
    float* o = (float*)d_out;

    const size_t elems = (size_t)BH_N * PER_BH;              // 4,194,304
    const size_t need  = 2 * elems * sizeof(unsigned short); // 16.78 MB

    if (ws_size >= need) {
        unsigned short* kbf = (unsigned short*)d_ws;
        unsigned short* vtb = kbf + elems;
        prepass_kernel<<<dim3(S_LEN / 64, BH_N), 256, 0, stream>>>(k, v, kbf, vtb);
        poly_attn_main<<<dim3(S_LEN / BQ, BH_N), 256, 0, stream>>>(q, kbf, vtb, o);
    } else {
        poly_attn_fallback<<<dim3(S_LEN / 64, BH_N), 256, 0, stream>>>(q, k, v, o);
    }
}